// Round 1
// baseline (560.851 us; speedup 1.0000x reference)
//
#include <hip/hip_runtime.h>

// Problem constants
#define N_NODES   300000
#define K_STENCIL 27
#define CIN       32
#define COUT      64
#define BN_EPS    1e-5f

// Workspace layout (bytes):
//   [0, 32768)           : split stats, 64 splits x (sum[64], sumsq[64]) fp32
//   [32768, 33280)       : ab coeffs a[64], b[64] fp32
//   [33280, 143872)      : weightT bf16 [27][64][32]
//   [143872, 19343872)   : data bf16 [N][32]  (only if ws_size permits)
#define WS_STATS_OFF 0
#define WS_AB_OFF    32768
#define WS_WT_OFF    33280
#define WS_DATA_OFF  143872
#define N_SPLITS     64

typedef short bf16x8 __attribute__((ext_vector_type(8)));
typedef float f32x4  __attribute__((ext_vector_type(4)));

__device__ __forceinline__ short f2bf_rne(float f) {
    unsigned u = __builtin_bit_cast(unsigned, f);
    u += 0x7fffu + ((u >> 16) & 1u);   // round-to-nearest-even
    return (short)(u >> 16);
}

// ---------------------------------------------------------------------------
// prep: zero split-stats + weight [27][32][64] fp32 -> weightT [27][64][32]
// bf16 + (optionally) data [N][32] fp32 -> bf16 table. Data task: 8 elems /
// thread (2x float4 load -> 1x 16B bf16x8 store), 1.2M threads.
// ---------------------------------------------------------------------------
__global__ __launch_bounds__(256) void prep(const float* __restrict__ w,
                                            unsigned short* __restrict__ wT,
                                            float* __restrict__ stats,
                                            const float* __restrict__ data,
                                            unsigned short* __restrict__ dataB,
                                            int doData) {
    int t = blockIdx.x * blockDim.x + threadIdx.x;
    if (t < N_SPLITS * 128) stats[t] = 0.f;
    if (t < K_STENCIL * COUT * CIN) {
        int c = t & (CIN - 1);
        int o = (t >> 5) & (COUT - 1);
        int k = t >> 11;
        wT[t] = (unsigned short)f2bf_rne(w[(k * CIN + c) * COUT + o]);
    }
    if (doData && t < N_NODES * CIN / 8) {
        const f32x4* src = (const f32x4*)data + (size_t)t * 2;
        f32x4 a = src[0], b = src[1];
        bf16x8 o8;
        #pragma unroll
        for (int j = 0; j < 4; ++j) {
            o8[j]     = f2bf_rne(a[j]);
            o8[j + 4] = f2bf_rne(b[j]);
        }
        ((bf16x8*)dataB)[t] = o8;
    }
}

// ---------------------------------------------------------------------------
// bf16-gather conv: one dwordx4 per tap IS the A-fragment. All 27 neighbor
// indices loaded up-front, all 27 gathers issued into a live pay[27] array,
// sched_barrier(0) pins them before the MFMA drain so the compiler cannot
// register-minimize the pipeline (R5/R0 evidence: without live arrays it
// drops to ~4 outstanding gathers -> 2.3 TB/s latency-bound). BN split-stats
// fused into the epilogue (tail rows produce exact zeros -> no guard needed).
// ---------------------------------------------------------------------------
__global__ __launch_bounds__(256, 2) void conv_bf16(
        const unsigned short* __restrict__ dataB, const int* __restrict__ neigh,
        const unsigned short* __restrict__ wT, float* __restrict__ out,
        float* __restrict__ stats) {
    const int wave  = threadIdx.x >> 6;
    const int lane  = threadIdx.x & 63;
    const int row16 = lane & 15;
    const int quad  = lane >> 4;

    __shared__ float lsum[COUT];
    __shared__ float lsq[COUT];
    if (threadIdx.x < COUT) { lsum[threadIdx.x] = 0.f; lsq[threadIdx.x] = 0.f; }

    // ---- layout probe: D = I*T, T[k][n]=k*16+n -> slot value encodes (m,n)
    bf16x8 ia, tb;
    #pragma unroll
    for (int j = 0; j < 8; ++j) {
        int k = quad * 8 + j;
        ia[j] = (k == row16) ? (short)0x3F80 : (short)0;
        tb[j] = f2bf_rne((float)(k * 16 + row16));
    }
    f32x4 pacc = {0.f, 0.f, 0.f, 0.f};
    pacc = __builtin_amdgcn_mfma_f32_16x16x32_bf16(ia, tb, pacc, 0, 0, 0);
    int mrow[4], ncol[4];
    #pragma unroll
    for (int r = 0; r < 4; ++r) {
        int iv = (int)(pacc[r] + 0.5f);
        mrow[r] = (iv >> 4) & 15;
        ncol[r] = iv & 15;
    }

    // ---- main gather-GEMM ----
    const int node   = blockIdx.x * 64 + wave * 16 + row16;
    const bool valid = (node < N_NODES);
    const int nclamp = valid ? node : 0;
    const int* nrow  = neigh + (size_t)nclamp * K_STENCIL;

    // 1) all 27 neighbor indices (27*4=108B row, 4B-aligned -> scalar dwords)
    int kid[K_STENCIL];
    #pragma unroll
    for (int j = 0; j < K_STENCIL; ++j) kid[j] = nrow[j];

    // 2) all 27 gathers live-in-flight: 16B = the full A-fragment per tap
    const bf16x8 zfrag = {0, 0, 0, 0, 0, 0, 0, 0};
    bf16x8 pay[K_STENCIL];
    #pragma unroll
    for (int j = 0; j < K_STENCIL; ++j) {
        int idx = kid[j];
        if (valid && idx >= 0)
            pay[j] = *(const bf16x8*)(dataB + (size_t)idx * CIN + quad * 8);
        else
            pay[j] = zfrag;
    }
    __builtin_amdgcn_sched_barrier(0);   // pin: no MFMA hoisted above issues

    // 3) drain through 108 MFMAs
    f32x4 acc[4] = {f32x4{0,0,0,0}, f32x4{0,0,0,0}, f32x4{0,0,0,0}, f32x4{0,0,0,0}};
    const unsigned short* wbase = wT + row16 * CIN + quad * 8;
    #pragma unroll
    for (int j = 0; j < K_STENCIL; ++j) {
        const unsigned short* wk = wbase + j * (COUT * CIN);
        #pragma unroll
        for (int ct = 0; ct < 4; ++ct) {
            bf16x8 bfrag = *(const bf16x8*)(wk + ct * 16 * CIN);
            acc[ct] = __builtin_amdgcn_mfma_f32_16x16x32_bf16(pay[j], bfrag, acc[ct], 0, 0, 0);
        }
    }

    // ---- epilogue: write out + fused BN split-stats ----
    __syncthreads();   // lsum/lsq init visible before atomics
    const int tilebase = blockIdx.x * 64 + wave * 16;
    #pragma unroll
    for (int ct = 0; ct < 4; ++ct) {
        #pragma unroll
        for (int r = 0; r < 4; ++r) {
            int n_out = tilebase + mrow[r];
            int col   = ct * 16 + ncol[r];
            float v   = acc[ct][r];          // invalid rows: exact 0.0
            if (n_out < N_NODES)
                out[(size_t)n_out * COUT + col] = v;
            atomicAdd(&lsum[col], v);
            atomicAdd(&lsq[col], v * v);
        }
    }
    __syncthreads();
    if (threadIdx.x < 128) {
        int split = blockIdx.x & (N_SPLITS - 1);
        float v = (threadIdx.x < 64) ? lsum[threadIdx.x] : lsq[threadIdx.x - 64];
        atomicAdd(&stats[split * 128 + threadIdx.x], v);
    }
}

// ---------------------------------------------------------------------------
// fp32-gather fallback (if ws_size can't hold the bf16 data table) — the
// R0-proven 3x9 pipelined kernel, now with fused BN split-stats epilogue.
// ---------------------------------------------------------------------------
__global__ __launch_bounds__(256, 2) void conv_f32(
        const float* __restrict__ data, const int* __restrict__ neigh,
        const unsigned short* __restrict__ wT, float* __restrict__ out,
        float* __restrict__ stats) {
    const int wave  = threadIdx.x >> 6;
    const int lane  = threadIdx.x & 63;
    const int row16 = lane & 15;
    const int quad  = lane >> 4;

    __shared__ float lsum[COUT];
    __shared__ float lsq[COUT];
    if (threadIdx.x < COUT) { lsum[threadIdx.x] = 0.f; lsq[threadIdx.x] = 0.f; }

    bf16x8 ia, tb;
    #pragma unroll
    for (int j = 0; j < 8; ++j) {
        int k = quad * 8 + j;
        ia[j] = (k == row16) ? (short)0x3F80 : (short)0;
        tb[j] = f2bf_rne((float)(k * 16 + row16));
    }
    f32x4 pacc = {0.f, 0.f, 0.f, 0.f};
    pacc = __builtin_amdgcn_mfma_f32_16x16x32_bf16(ia, tb, pacc, 0, 0, 0);
    int mrow[4], ncol[4];
    #pragma unroll
    for (int r = 0; r < 4; ++r) {
        int iv = (int)(pacc[r] + 0.5f);
        mrow[r] = (iv >> 4) & 15;
        ncol[r] = iv & 15;
    }

    const int node   = blockIdx.x * 64 + wave * 16 + row16;
    const bool valid = (node < N_NODES);
    const int nclamp = valid ? node : 0;

    f32x4 acc[4] = {f32x4{0,0,0,0}, f32x4{0,0,0,0}, f32x4{0,0,0,0}, f32x4{0,0,0,0}};
    const int* nrow = neigh + nclamp * K_STENCIL;

    #pragma unroll
    for (int g = 0; g < 3; ++g) {
        int kid[9];
        #pragma unroll
        for (int j = 0; j < 9; ++j) kid[j] = nrow[g * 9 + j];

        f32x4 lo[9], hi[9];
        #pragma unroll
        for (int j = 0; j < 9; ++j) {
            int idx = kid[j];
            if (valid && idx >= 0) {
                const f32x4* drow = (const f32x4*)(data + (size_t)idx * CIN + quad * 8);
                lo[j] = drow[0];
                hi[j] = drow[1];
            } else {
                lo[j] = f32x4{0, 0, 0, 0};
                hi[j] = f32x4{0, 0, 0, 0};
            }
        }

        #pragma unroll
        for (int j = 0; j < 9; ++j) {
            bf16x8 afrag;
            #pragma unroll
            for (int t = 0; t < 4; ++t) {
                afrag[t]     = f2bf_rne(lo[j][t]);
                afrag[t + 4] = f2bf_rne(hi[j][t]);
            }
            const unsigned short* wk = wT + (g * 9 + j) * (COUT * CIN) + row16 * CIN + quad * 8;
            #pragma unroll
            for (int ct = 0; ct < 4; ++ct) {
                bf16x8 bfrag = *(const bf16x8*)(wk + ct * 16 * CIN);
                acc[ct] = __builtin_amdgcn_mfma_f32_16x16x32_bf16(afrag, bfrag, acc[ct], 0, 0, 0);
            }
        }
    }

    __syncthreads();
    const int tilebase = blockIdx.x * 64 + wave * 16;
    #pragma unroll
    for (int ct = 0; ct < 4; ++ct) {
        #pragma unroll
        for (int r = 0; r < 4; ++r) {
            int n_out = tilebase + mrow[r];
            int col   = ct * 16 + ncol[r];
            float v   = acc[ct][r];
            if (n_out < N_NODES)
                out[(size_t)n_out * COUT + col] = v;
            atomicAdd(&lsum[col], v);
            atomicAdd(&lsq[col], v * v);
        }
    }
    __syncthreads();
    if (threadIdx.x < 128) {
        int split = blockIdx.x & (N_SPLITS - 1);
        float v = (threadIdx.x < 64) ? lsum[threadIdx.x] : lsq[threadIdx.x - 64];
        atomicAdd(&stats[split * 128 + threadIdx.x], v);
    }
}

// ---------------------------------------------------------------------------
__global__ void finalize_stats(const float* __restrict__ stats,
                               const float* __restrict__ gamma,
                               const float* __restrict__ beta,
                               float* __restrict__ ab) {
    int o = threadIdx.x;  // 64 threads
    if (o >= COUT) return;
    float s = 0.f, q = 0.f;
    for (int sp = 0; sp < N_SPLITS; ++sp) {
        s += stats[sp * 128 + o];
        q += stats[sp * 128 + 64 + o];
    }
    float inv_n = 1.0f / (float)N_NODES;
    float mean = s * inv_n;
    float var  = q * inv_n - mean * mean;
    float a = gamma[o] * rsqrtf(var + BN_EPS);
    float b = beta[o] - mean * a;
    ab[o] = a;
    ab[64 + o] = b;
}

// ---------------------------------------------------------------------------
__global__ __launch_bounds__(256) void bn_relu(float* __restrict__ out,
                                               const float* __restrict__ ab) {
    int i = blockIdx.x * blockDim.x + threadIdx.x;  // float4 index, exact grid
    f32x4 a = ((const f32x4*)ab)[i & 15];
    f32x4 b = ((const f32x4*)(ab + 64))[i & 15];
    f32x4 v = ((f32x4*)out)[i];
    #pragma unroll
    for (int j = 0; j < 4; ++j) {
        float y = v[j] * a[j] + b[j];
        v[j] = y > 0.f ? y : 0.f;
    }
    ((f32x4*)out)[i] = v;
}

// ---------------------------------------------------------------------------
extern "C" void kernel_launch(void* const* d_in, const int* in_sizes, int n_in,
                              void* d_out, int out_size, void* d_ws, size_t ws_size,
                              hipStream_t stream) {
    const float* data   = (const float*)d_in[0];
    const int*   neigh  = (const int*)d_in[1];     // int32 on device
    const float* weight = (const float*)d_in[2];
    const float* gamma  = (const float*)d_in[3];
    const float* beta   = (const float*)d_in[4];
    float* out = (float*)d_out;

    char* ws = (char*)d_ws;
    float*          stats = (float*)(ws + WS_STATS_OFF);
    float*          ab    = (float*)(ws + WS_AB_OFF);
    unsigned short* wT    = (unsigned short*)(ws + WS_WT_OFF);
    unsigned short* dataB = (unsigned short*)(ws + WS_DATA_OFF);

    const size_t need_bf16 = (size_t)WS_DATA_OFF + (size_t)N_NODES * CIN * 2;
    const int useBf16 = (ws_size >= need_bf16) ? 1 : 0;

    // prep grid: covers data-pack task (1.2M threads) when bf16 path active
    const int prepGrid = useBf16 ? (N_NODES * CIN / 8 + 255) / 256
                                 : (K_STENCIL * COUT * CIN + 255) / 256;
    prep<<<prepGrid, 256, 0, stream>>>(weight, wT, stats, data, dataB, useBf16);

    const int grid = (N_NODES + 63) / 64;  // 4688
    if (useBf16)
        conv_bf16<<<grid, 256, 0, stream>>>(dataB, neigh, wT, out, stats);
    else
        conv_f32<<<grid, 256, 0, stream>>>(data, neigh, wT, out, stats);

    finalize_stats<<<1, 64, 0, stream>>>(stats, gamma, beta, ab);

    int total4 = N_NODES * COUT / 4;  // 4,800,000
    bn_relu<<<total4 / 256, 256, 0, stream>>>(out, ab);
}

// Round 3
// 541.371 us; speedup vs baseline: 1.0360x; 1.0360x over previous
//
#include <hip/hip_runtime.h>

// Problem constants
#define N_NODES   300000
#define K_STENCIL 27
#define CIN       32
#define COUT      64
#define BN_EPS    1e-5f

// Workspace layout (bytes):
//   [0, 32768)           : split stats, 64 splits x (sum[64], sumsq[64]) fp32
//   [32768, 33280)       : ab coeffs a[64], b[64] fp32
//   [33280, 143872)      : weightT bf16 [27][64][32]
//   [143872, 19343872)   : data bf16 [N][32]  (only if ws_size permits)
#define WS_STATS_OFF 0
#define WS_AB_OFF    32768
#define WS_WT_OFF    33280
#define WS_DATA_OFF  143872
#define N_SPLITS     64

typedef short bf16x8 __attribute__((ext_vector_type(8)));
typedef float f32x4  __attribute__((ext_vector_type(4)));

__device__ __forceinline__ short f2bf_rne(float f) {
    unsigned u = __builtin_bit_cast(unsigned, f);
    u += 0x7fffu + ((u >> 16) & 1u);   // round-to-nearest-even
    return (short)(u >> 16);
}

// ---------------------------------------------------------------------------
// prep: zero split-stats + weight [27][32][64] fp32 -> weightT [27][64][32]
// bf16 + (optionally) data [N][32] fp32 -> bf16 table. Data task: 8 elems /
// thread (2x float4 load -> 1x 16B bf16x8 store), 1.2M threads.
// ---------------------------------------------------------------------------
__global__ __launch_bounds__(256) void prep(const float* __restrict__ w,
                                            unsigned short* __restrict__ wT,
                                            float* __restrict__ stats,
                                            const float* __restrict__ data,
                                            unsigned short* __restrict__ dataB,
                                            int doData) {
    int t = blockIdx.x * blockDim.x + threadIdx.x;
    if (t < N_SPLITS * 128) stats[t] = 0.f;
    if (t < K_STENCIL * COUT * CIN) {
        int c = t & (CIN - 1);
        int o = (t >> 5) & (COUT - 1);
        int k = t >> 11;
        wT[t] = (unsigned short)f2bf_rne(w[(k * CIN + c) * COUT + o]);
    }
    if (doData && t < N_NODES * CIN / 8) {
        const f32x4* src = (const f32x4*)data + (size_t)t * 2;
        f32x4 a = src[0], b = src[1];
        bf16x8 o8;
        #pragma unroll
        for (int j = 0; j < 4; ++j) {
            o8[j]     = f2bf_rne(a[j]);
            o8[j + 4] = f2bf_rne(b[j]);
        }
        ((bf16x8*)dataB)[t] = o8;
    }
}

// ---------------------------------------------------------------------------
// bf16-gather conv, R2 schedule: back to the R0-proven grouped-live-array
// idiom (NO sched_barrier — R1 showed pinning 27 live loads past what RA
// will grant serializes every gather: VGPR=80, request rate -3.3x). Groups
// of 9 taps, one 16B dwordx4 per tap IS the A-fragment; depth-2 lookahead:
// group g+1's loads are issued in source order BEFORE group g's MFMA drain,
// double-buffered in statically-indexed register arrays (~72 VGPR payload,
// within the (256,2) budget). BN split-stats fused in epilogue.
// ---------------------------------------------------------------------------
__global__ __launch_bounds__(256, 2) void conv_bf16(
        const unsigned short* __restrict__ dataB, const int* __restrict__ neigh,
        const unsigned short* __restrict__ wT, float* __restrict__ out,
        float* __restrict__ stats) {
    const int wave  = threadIdx.x >> 6;
    const int lane  = threadIdx.x & 63;
    const int row16 = lane & 15;
    const int quad  = lane >> 4;

    __shared__ float lsum[COUT];
    __shared__ float lsq[COUT];
    if (threadIdx.x < COUT) { lsum[threadIdx.x] = 0.f; lsq[threadIdx.x] = 0.f; }

    // ---- layout probe: D = I*T, T[k][n]=k*16+n -> slot value encodes (m,n)
    bf16x8 ia, tb;
    #pragma unroll
    for (int j = 0; j < 8; ++j) {
        int k = quad * 8 + j;
        ia[j] = (k == row16) ? (short)0x3F80 : (short)0;
        tb[j] = f2bf_rne((float)(k * 16 + row16));
    }
    f32x4 pacc = {0.f, 0.f, 0.f, 0.f};
    pacc = __builtin_amdgcn_mfma_f32_16x16x32_bf16(ia, tb, pacc, 0, 0, 0);
    int mrow[4], ncol[4];
    #pragma unroll
    for (int r = 0; r < 4; ++r) {
        int iv = (int)(pacc[r] + 0.5f);
        mrow[r] = (iv >> 4) & 15;
        ncol[r] = iv & 15;
    }

    // ---- main gather-GEMM ----
    const int node   = blockIdx.x * 64 + wave * 16 + row16;
    const bool valid = (node < N_NODES);
    const int nclamp = valid ? node : 0;
    const int* nrow  = neigh + (size_t)nclamp * K_STENCIL;
    const bf16x8 zfrag = {0, 0, 0, 0, 0, 0, 0, 0};

    f32x4 acc[4] = {f32x4{0,0,0,0}, f32x4{0,0,0,0}, f32x4{0,0,0,0}, f32x4{0,0,0,0}};
    const unsigned short* wbase = wT + row16 * CIN + quad * 8;

// issue 9 neighbor-index loads + 9 gather dwordx4 into live array P
#define LOADG(P, KID, G)                                                      \
    _Pragma("unroll")                                                         \
    for (int j = 0; j < 9; ++j) KID[j] = nrow[(G) * 9 + j];                   \
    _Pragma("unroll")                                                         \
    for (int j = 0; j < 9; ++j) {                                             \
        int idx = KID[j];                                                     \
        if (valid && idx >= 0)                                                \
            P[j] = *(const bf16x8*)(dataB + (size_t)idx * CIN + quad * 8);    \
        else                                                                  \
            P[j] = zfrag;                                                     \
    }

// drain one group: 9 taps x 4 MFMAs
#define DRAING(P, G)                                                          \
    _Pragma("unroll")                                                         \
    for (int j = 0; j < 9; ++j) {                                             \
        const unsigned short* wk = wbase + ((G) * 9 + j) * (COUT * CIN);      \
        _Pragma("unroll")                                                     \
        for (int ct = 0; ct < 4; ++ct) {                                      \
            bf16x8 bfrag = *(const bf16x8*)(wk + ct * 16 * CIN);              \
            acc[ct] = __builtin_amdgcn_mfma_f32_16x16x32_bf16(P[j], bfrag,    \
                                                              acc[ct], 0, 0, 0); \
        }                                                                     \
    }

    int kidA[9], kidB[9], kidC[9];
    bf16x8 pA[9], pB[9], pC[9];

    LOADG(pA, kidA, 0)      // group 0 in flight
    LOADG(pB, kidB, 1)      // group 1 in flight (depth-2)
    DRAING(pA, 0)           // drain 0 while 1 flies
    LOADG(pC, kidC, 2)      // group 2 in flight
    DRAING(pB, 1)           // drain 1 while 2 flies
    DRAING(pC, 2)           // drain 2

#undef LOADG
#undef DRAING

    // ---- epilogue: write out + fused BN split-stats ----
    __syncthreads();   // lsum/lsq init visible before atomics
    const int tilebase = blockIdx.x * 64 + wave * 16;
    #pragma unroll
    for (int ct = 0; ct < 4; ++ct) {
        #pragma unroll
        for (int r = 0; r < 4; ++r) {
            int n_out = tilebase + mrow[r];
            int col   = ct * 16 + ncol[r];
            float v   = acc[ct][r];          // invalid rows: exact 0.0
            if (n_out < N_NODES)
                out[(size_t)n_out * COUT + col] = v;
            atomicAdd(&lsum[col], v);
            atomicAdd(&lsq[col], v * v);
        }
    }
    __syncthreads();
    if (threadIdx.x < 128) {
        int split = blockIdx.x & (N_SPLITS - 1);
        float v = (threadIdx.x < 64) ? lsum[threadIdx.x] : lsq[threadIdx.x - 64];
        atomicAdd(&stats[split * 128 + threadIdx.x], v);
    }
}

// ---------------------------------------------------------------------------
// fp32-gather fallback (if ws_size can't hold the bf16 data table) — the
// R0-proven 3x9 pipelined kernel with fused BN split-stats epilogue.
// ---------------------------------------------------------------------------
__global__ __launch_bounds__(256, 2) void conv_f32(
        const float* __restrict__ data, const int* __restrict__ neigh,
        const unsigned short* __restrict__ wT, float* __restrict__ out,
        float* __restrict__ stats) {
    const int wave  = threadIdx.x >> 6;
    const int lane  = threadIdx.x & 63;
    const int row16 = lane & 15;
    const int quad  = lane >> 4;

    __shared__ float lsum[COUT];
    __shared__ float lsq[COUT];
    if (threadIdx.x < COUT) { lsum[threadIdx.x] = 0.f; lsq[threadIdx.x] = 0.f; }

    bf16x8 ia, tb;
    #pragma unroll
    for (int j = 0; j < 8; ++j) {
        int k = quad * 8 + j;
        ia[j] = (k == row16) ? (short)0x3F80 : (short)0;
        tb[j] = f2bf_rne((float)(k * 16 + row16));
    }
    f32x4 pacc = {0.f, 0.f, 0.f, 0.f};
    pacc = __builtin_amdgcn_mfma_f32_16x16x32_bf16(ia, tb, pacc, 0, 0, 0);
    int mrow[4], ncol[4];
    #pragma unroll
    for (int r = 0; r < 4; ++r) {
        int iv = (int)(pacc[r] + 0.5f);
        mrow[r] = (iv >> 4) & 15;
        ncol[r] = iv & 15;
    }

    const int node   = blockIdx.x * 64 + wave * 16 + row16;
    const bool valid = (node < N_NODES);
    const int nclamp = valid ? node : 0;

    f32x4 acc[4] = {f32x4{0,0,0,0}, f32x4{0,0,0,0}, f32x4{0,0,0,0}, f32x4{0,0,0,0}};
    const int* nrow = neigh + nclamp * K_STENCIL;

    #pragma unroll
    for (int g = 0; g < 3; ++g) {
        int kid[9];
        #pragma unroll
        for (int j = 0; j < 9; ++j) kid[j] = nrow[g * 9 + j];

        f32x4 lo[9], hi[9];
        #pragma unroll
        for (int j = 0; j < 9; ++j) {
            int idx = kid[j];
            if (valid && idx >= 0) {
                const f32x4* drow = (const f32x4*)(data + (size_t)idx * CIN + quad * 8);
                lo[j] = drow[0];
                hi[j] = drow[1];
            } else {
                lo[j] = f32x4{0, 0, 0, 0};
                hi[j] = f32x4{0, 0, 0, 0};
            }
        }

        #pragma unroll
        for (int j = 0; j < 9; ++j) {
            bf16x8 afrag;
            #pragma unroll
            for (int t = 0; t < 4; ++t) {
                afrag[t]     = f2bf_rne(lo[j][t]);
                afrag[t + 4] = f2bf_rne(hi[j][t]);
            }
            const unsigned short* wk = wT + (g * 9 + j) * (COUT * CIN) + row16 * CIN + quad * 8;
            #pragma unroll
            for (int ct = 0; ct < 4; ++ct) {
                bf16x8 bfrag = *(const bf16x8*)(wk + ct * 16 * CIN);
                acc[ct] = __builtin_amdgcn_mfma_f32_16x16x32_bf16(afrag, bfrag, acc[ct], 0, 0, 0);
            }
        }
    }

    __syncthreads();
    const int tilebase = blockIdx.x * 64 + wave * 16;
    #pragma unroll
    for (int ct = 0; ct < 4; ++ct) {
        #pragma unroll
        for (int r = 0; r < 4; ++r) {
            int n_out = tilebase + mrow[r];
            int col   = ct * 16 + ncol[r];
            float v   = acc[ct][r];
            if (n_out < N_NODES)
                out[(size_t)n_out * COUT + col] = v;
            atomicAdd(&lsum[col], v);
            atomicAdd(&lsq[col], v * v);
        }
    }
    __syncthreads();
    if (threadIdx.x < 128) {
        int split = blockIdx.x & (N_SPLITS - 1);
        float v = (threadIdx.x < 64) ? lsum[threadIdx.x] : lsq[threadIdx.x - 64];
        atomicAdd(&stats[split * 128 + threadIdx.x], v);
    }
}

// ---------------------------------------------------------------------------
__global__ void finalize_stats(const float* __restrict__ stats,
                               const float* __restrict__ gamma,
                               const float* __restrict__ beta,
                               float* __restrict__ ab) {
    int o = threadIdx.x;  // 64 threads
    if (o >= COUT) return;
    float s = 0.f, q = 0.f;
    for (int sp = 0; sp < N_SPLITS; ++sp) {
        s += stats[sp * 128 + o];
        q += stats[sp * 128 + 64 + o];
    }
    float inv_n = 1.0f / (float)N_NODES;
    float mean = s * inv_n;
    float var  = q * inv_n - mean * mean;
    float a = gamma[o] * rsqrtf(var + BN_EPS);
    float b = beta[o] - mean * a;
    ab[o] = a;
    ab[64 + o] = b;
}

// ---------------------------------------------------------------------------
__global__ __launch_bounds__(256) void bn_relu(float* __restrict__ out,
                                               const float* __restrict__ ab) {
    int i = blockIdx.x * blockDim.x + threadIdx.x;  // float4 index, exact grid
    f32x4 a = ((const f32x4*)ab)[i & 15];
    f32x4 b = ((const f32x4*)(ab + 64))[i & 15];
    f32x4 v = ((f32x4*)out)[i];
    #pragma unroll
    for (int j = 0; j < 4; ++j) {
        float y = v[j] * a[j] + b[j];
        v[j] = y > 0.f ? y : 0.f;
    }
    ((f32x4*)out)[i] = v;
}

// ---------------------------------------------------------------------------
extern "C" void kernel_launch(void* const* d_in, const int* in_sizes, int n_in,
                              void* d_out, int out_size, void* d_ws, size_t ws_size,
                              hipStream_t stream) {
    const float* data   = (const float*)d_in[0];
    const int*   neigh  = (const int*)d_in[1];     // int32 on device
    const float* weight = (const float*)d_in[2];
    const float* gamma  = (const float*)d_in[3];
    const float* beta   = (const float*)d_in[4];
    float* out = (float*)d_out;

    char* ws = (char*)d_ws;
    float*          stats = (float*)(ws + WS_STATS_OFF);
    float*          ab    = (float*)(ws + WS_AB_OFF);
    unsigned short* wT    = (unsigned short*)(ws + WS_WT_OFF);
    unsigned short* dataB = (unsigned short*)(ws + WS_DATA_OFF);

    const size_t need_bf16 = (size_t)WS_DATA_OFF + (size_t)N_NODES * CIN * 2;
    const int useBf16 = (ws_size >= need_bf16) ? 1 : 0;

    // prep grid: covers data-pack task (1.2M threads) when bf16 path active
    const int prepGrid = useBf16 ? (N_NODES * CIN / 8 + 255) / 256
                                 : (K_STENCIL * COUT * CIN + 255) / 256;
    prep<<<prepGrid, 256, 0, stream>>>(weight, wT, stats, data, dataB, useBf16);

    const int grid = (N_NODES + 63) / 64;  // 4688
    if (useBf16)
        conv_bf16<<<grid, 256, 0, stream>>>(dataB, neigh, wT, out, stats);
    else
        conv_f32<<<grid, 256, 0, stream>>>(data, neigh, wT, out, stats);

    finalize_stats<<<1, 64, 0, stream>>>(stats, gamma, beta, ab);

    int total4 = N_NODES * COUT / 4;  // 4,800,000
    bn_relu<<<total4 / 256, 256, 0, stream>>>(out, ab);
}